// Round 6
// baseline (89.266 us; speedup 1.0000x reference)
//
#include <hip/hip_runtime.h>
#include <math.h>

// X[8192,64], Y[8192,64] fp32.
// d2[i][j] = x2_i + y2_j - 2<x_i,y_j>;  out = mean_i sqrt(min_j d2) + mean_j sqrt(min_i d2)
//
// R6: TWO kernels (was 3) — each mine block converts fp32->bf16 privately:
//  - A frags loaded fp32 directly in MFMA layout, squared+converted in-reg;
//    x2 per acc-row obtained via shfl gather. No prep kernel, no bf16 ws array.
//  - B chunks staged fp32->LDS bf16; y2 computed during staging (3-shfl reduce).
//  - Partial-min slabs carry x2/y2 folded in: rslab = x2 + min(y2-2s),
//    cslab = y2 + min(x2-2s); finish needs only sqrt(max(.,0)) + mean.
//  - No atomics in mine; every slab slot written exactly once (0xAA-poison safe).
// Fixed floor: harness re-poisons the 268 MB d_ws inside the timed window
// (~41 us fill) — not controllable from here.

#define NROWS 8192
#define DDIM  64
#define CHUNKS 8      // 8 x 128 j per block; 512 blocks = 64 itiles x 8 slices
#define LSTR 72       // LDS row stride (bf16): 144 B, 16B-aligned, even bank spread

typedef __bf16 bf16_t;
typedef bf16_t bf16x8 __attribute__((ext_vector_type(8)));
typedef float  f32x4  __attribute__((ext_vector_type(4)));

// ws floats: rslab[8][8192][2] (512 KB) | cslab[128][8192] (4 MB)

__global__ __launch_bounds__(256, 2)
void mine_kernel(const float* __restrict__ X, const float* __restrict__ Y,
                 float* __restrict__ rslab, float* __restrict__ cslab,
                 float* __restrict__ out) {
  __shared__ bf16_t Ys[128 * LSTR];   // 18 KB
  __shared__ float y2s[128];

  const int tid = threadIdx.x;
  const int L = tid & 63;
  const int w = tid >> 6;
  const int lr = L & 15;
  const int q  = L >> 4;
  const int rh = w >> 1, ch = w & 1;
  const int itile = blockIdx.x & 63;
  const int slice = blockIdx.x >> 6;        // 0..7
  const int i0 = itile * 128;
  const int rgb = rh * 64, cgb = ch * 64;
  const int jbase = slice * (CHUNKS * 128);

  if (blockIdx.x == 0 && tid == 0) out[0] = 0.f;  // finish adds after we finish

  // ---- A: fp32 load in fragment layout, square-sum, convert ----
  bf16x8 Af[8];
  float x2r[16];
  {
    float x2acc[4];
#pragma unroll
    for (int a = 0; a < 4; ++a) {
      const float4* rp = (const float4*)(X + (i0 + rgb + a * 16 + lr) * DDIM);
      float4 u0 = rp[q * 2],     u1 = rp[q * 2 + 1];      // k = q*8..q*8+7
      float4 u2 = rp[8 + q * 2], u3 = rp[8 + q * 2 + 1];  // k = 32+q*8..
      float s = 0.f;
      s = fmaf(u0.x, u0.x, s); s = fmaf(u0.y, u0.y, s);
      s = fmaf(u0.z, u0.z, s); s = fmaf(u0.w, u0.w, s);
      s = fmaf(u1.x, u1.x, s); s = fmaf(u1.y, u1.y, s);
      s = fmaf(u1.z, u1.z, s); s = fmaf(u1.w, u1.w, s);
      s = fmaf(u2.x, u2.x, s); s = fmaf(u2.y, u2.y, s);
      s = fmaf(u2.z, u2.z, s); s = fmaf(u2.w, u2.w, s);
      s = fmaf(u3.x, u3.x, s); s = fmaf(u3.y, u3.y, s);
      s = fmaf(u3.z, u3.z, s); s = fmaf(u3.w, u3.w, s);
      Af[a * 2 + 0] = (bf16x8){(bf16_t)u0.x, (bf16_t)u0.y, (bf16_t)u0.z, (bf16_t)u0.w,
                               (bf16_t)u1.x, (bf16_t)u1.y, (bf16_t)u1.z, (bf16_t)u1.w};
      Af[a * 2 + 1] = (bf16x8){(bf16_t)u2.x, (bf16_t)u2.y, (bf16_t)u2.z, (bf16_t)u2.w,
                               (bf16_t)u3.x, (bf16_t)u3.y, (bf16_t)u3.z, (bf16_t)u3.w};
      s += __shfl_xor(s, 16, 64);   // reduce over q -> full row sum at (lr)
      s += __shfl_xor(s, 32, 64);
      x2acc[a] = s;                 // x2 of row a*16+lr
    }
    // epilogue rows are a*16+q*4+p -> gather from lane (q*4+p)
#pragma unroll
    for (int a = 0; a < 4; ++a)
#pragma unroll
      for (int p = 0; p < 4; ++p)
        x2r[a * 4 + p] = __shfl(x2acc[a], q * 4 + p, 64);
  }

  float rmin[16];
#pragma unroll
  for (int k = 0; k < 16; ++k) rmin[k] = INFINITY;

  for (int cc = 0; cc < CHUNKS; ++cc) {
    const int j0 = jbase + cc * 128;
    __syncthreads();            // prior chunk's LDS fully consumed
    // ---- stage B chunk: fp32 -> bf16 LDS + y2 in LDS ----
#pragma unroll
    for (int p = 0; p < 4; ++p) {
      int f = p * 256 + tid;
      int r = f >> 3, c = f & 7;
      const float4* yp = (const float4*)(Y + (j0 + r) * DDIM);
      float4 a0 = yp[c * 2], a1 = yp[c * 2 + 1];
      float s = 0.f;
      s = fmaf(a0.x, a0.x, s); s = fmaf(a0.y, a0.y, s);
      s = fmaf(a0.z, a0.z, s); s = fmaf(a0.w, a0.w, s);
      s = fmaf(a1.x, a1.x, s); s = fmaf(a1.y, a1.y, s);
      s = fmaf(a1.z, a1.z, s); s = fmaf(a1.w, a1.w, s);
      s += __shfl_xor(s, 1, 64);
      s += __shfl_xor(s, 2, 64);
      s += __shfl_xor(s, 4, 64);
      if ((tid & 7) == 0) y2s[r] = s;
      bf16x8 hv = {(bf16_t)a0.x, (bf16_t)a0.y, (bf16_t)a0.z, (bf16_t)a0.w,
                   (bf16_t)a1.x, (bf16_t)a1.y, (bf16_t)a1.z, (bf16_t)a1.w};
      *(bf16x8*)&Ys[r * LSTR + c * 8] = hv;
    }
    __syncthreads();

    float y2c[4];
#pragma unroll
    for (int b = 0; b < 4; ++b) y2c[b] = y2s[cgb + b * 16 + lr];

    f32x4 acc[4][4];
#pragma unroll
    for (int a = 0; a < 4; ++a)
#pragma unroll
      for (int b = 0; b < 4; ++b) acc[a][b] = (f32x4){0.f, 0.f, 0.f, 0.f};

#pragma unroll
    for (int b = 0; b < 4; ++b) {
      bf16x8 B0 = *(const bf16x8*)&Ys[(cgb + b * 16 + lr) * LSTR + q * 8];
      bf16x8 B1 = *(const bf16x8*)&Ys[(cgb + b * 16 + lr) * LSTR + 32 + q * 8];
#pragma unroll
      for (int a = 0; a < 4; ++a) {
        acc[a][b] = __builtin_amdgcn_mfma_f32_16x16x32_bf16(Af[a * 2 + 0], B0, acc[a][b], 0, 0, 0);
        acc[a][b] = __builtin_amdgcn_mfma_f32_16x16x32_bf16(Af[a * 2 + 1], B1, acc[a][b], 0, 0, 0);
      }
    }

    // ---- epilogue (C/D: col = lr within 16-group, row = q*4+p) ----
    float cmin[4] = {INFINITY, INFINITY, INFINITY, INFINITY};
#pragma unroll
    for (int a = 0; a < 4; ++a)
#pragma unroll
      for (int p = 0; p < 4; ++p) {
        float x2v = x2r[a * 4 + p];
        float t0 = fmaf(-2.f, acc[a][0][p], y2c[0]);
        float t1 = fmaf(-2.f, acc[a][1][p], y2c[1]);
        float t2 = fmaf(-2.f, acc[a][2][p], y2c[2]);
        float t3 = fmaf(-2.f, acc[a][3][p], y2c[3]);
        rmin[a * 4 + p] = fminf(rmin[a * 4 + p],
                                fminf(fminf(t0, t1), fminf(t2, t3)));
        cmin[0] = fminf(cmin[0], fmaf(-2.f, acc[a][0][p], x2v));
        cmin[1] = fminf(cmin[1], fmaf(-2.f, acc[a][1][p], x2v));
        cmin[2] = fminf(cmin[2], fmaf(-2.f, acc[a][2][p], x2v));
        cmin[3] = fminf(cmin[3], fmaf(-2.f, acc[a][3][p], x2v));
      }
#pragma unroll
    for (int b = 0; b < 4; ++b) {
      cmin[b] = fminf(cmin[b], __shfl_xor(cmin[b], 16, 64));
      cmin[b] = fminf(cmin[b], __shfl_xor(cmin[b], 32, 64));
    }
    float v = cmin[0], yv = y2c[0];
    if (q == 1) { v = cmin[1]; yv = y2c[1]; }
    else if (q == 2) { v = cmin[2]; yv = y2c[2]; }
    else if (q == 3) { v = cmin[3]; yv = y2c[3]; }
    // column j = j0 + cgb + L; fold y2 in so finish needs no y2 array
    cslab[(itile * 2 + rh) * NROWS + j0 + cgb + L] = v + yv;
  }

  // ---- row mins: reduce across 16 col-lanes, fold x2 in, store ----
#pragma unroll
  for (int a = 0; a < 4; ++a)
#pragma unroll
    for (int p = 0; p < 4; ++p) {
      float v = rmin[a * 4 + p];
      v = fminf(v, __shfl_xor(v, 1, 64));
      v = fminf(v, __shfl_xor(v, 2, 64));
      v = fminf(v, __shfl_xor(v, 4, 64));
      v = fminf(v, __shfl_xor(v, 8, 64));
      if (lr == 0)
        rslab[slice * (NROWS * 2) + (i0 + rgb + a * 16 + q * 4 + p) * 2 + ch] =
            v + x2r[a * 4 + p];
    }
}

// blocks [0,32): rows (256 each, 8x float2 coalesced). [32,160): cols (64 each,
// 4 segments x 32 partials, LDS combine). Slab values already include x2/y2.
__global__ void finish_kernel(const float* __restrict__ rslab,
                              const float* __restrict__ cslab,
                              float* __restrict__ out) {
  const int b = blockIdx.x;
  const int tid = threadIdx.x;
  if (b < 32) {
    int row = b * 256 + tid;
    float m = INFINITY;
#pragma unroll
    for (int g = 0; g < 8; ++g) {
      float2 v = *(const float2*)&rslab[g * (NROWS * 2) + row * 2];
      m = fminf(m, fminf(v.x, v.y));
    }
    float v = sqrtf(fmaxf(m, 0.f)) * (1.0f / 8192.0f);
#pragma unroll
    for (int off = 32; off > 0; off >>= 1) v += __shfl_down(v, off, 64);
    __shared__ float partial[4];
    if ((tid & 63) == 0) partial[tid >> 6] = v;
    __syncthreads();
    if (tid == 0)
      atomicAdd(out, partial[0] + partial[1] + partial[2] + partial[3]);
  } else {
    int j = (b - 32) * 64 + (tid & 63);
    int seg = tid >> 6;
    float m = INFINITY;
#pragma unroll
    for (int k = 0; k < 32; ++k)
      m = fminf(m, cslab[(seg * 32 + k) * NROWS + j]);
    __shared__ float red[4][64];
    red[seg][tid & 63] = m;
    __syncthreads();
    if (tid < 64) {
      float mc = fminf(fminf(red[0][tid], red[1][tid]),
                       fminf(red[2][tid], red[3][tid]));
      float v = sqrtf(fmaxf(mc, 0.f)) * (1.0f / 8192.0f);
#pragma unroll
      for (int off = 32; off > 0; off >>= 1) v += __shfl_down(v, off, 64);
      if (tid == 0) atomicAdd(out, v);
    }
  }
}

extern "C" void kernel_launch(void* const* d_in, const int* in_sizes, int n_in,
                              void* d_out, int out_size, void* d_ws, size_t ws_size,
                              hipStream_t stream) {
  const float* X = (const float*)d_in[0];
  const float* Y = (const float*)d_in[1];
  float* out = (float*)d_out;

  float* rslab = (float*)d_ws;                 // [8][8192][2]
  float* cslab = rslab + 8 * NROWS * 2;        // [128][8192]

  mine_kernel<<<512, 256, 0, stream>>>(X, Y, rslab, cslab, out);
  finish_kernel<<<160, 256, 0, stream>>>(rslab, cslab, out);
}

// Round 7
// 88.567 us; speedup vs baseline: 1.0079x; 1.0079x over previous
//
#include <hip/hip_runtime.h>
#include <math.h>

// X[8192,64], Y[8192,64] fp32.
// d2[i][j] = x2_i + y2_j - 2<x_i,y_j>;  out = mean_i sqrt(min_j d2) + mean_j sqrt(min_i d2)
//
// R7: 3 kernels. prep: fp32->bf16 + squares (removes all cvt/reduce VALU from
// mine's barrier-bounded path). mine: grid 2048 (64 itiles x 32 slices,
// CHUNKS=2), __launch_bounds__(256,3) -> 3 blocks/CU resident (unified-RF
// audit: acc 64 AGPR + ~95 arch < 170/wave for 3 waves/SIMD); A frags
// register-persistent, B single-buffer LDS (stage = pure b128 copy), x2 kept
// as 4 regs + shfl-at-use, y2 loads issued pre-barrier. Slabs carry x2/y2
// folded; every slot written exactly once (poison-safe, no atomics).
// finish: coalesced slab reduction + sqrt + mean.
// Fixed floor: harness's 268 MB d_ws 0xAA re-poison (~41 us) sits inside the
// timed window.

#define NROWS 8192
#define DDIM  64
#define ITILES 64
#define SLICES 32     // j: 32 slices x 256
#define CHUNKS 2      // 2 x 128 j per block
#define LSTR 72       // LDS row stride (bf16): 144 B, 16B-aligned, uniform banks

typedef __bf16 bf16_t;
typedef bf16_t bf16x8 __attribute__((ext_vector_type(8)));
typedef bf16_t bf16x4 __attribute__((ext_vector_type(4)));
typedef float  f32x4  __attribute__((ext_vector_type(4)));

// ws floats: rslab[32][8192][2] (2 MB) | cslab[128][8192] (4 MB)
// plus bf16: Xbf 1 MB | Ybf 1 MB | x2,y2 64 KB

__global__ void prep_kernel(const float* __restrict__ X,
                            const float* __restrict__ Y,
                            bf16_t* __restrict__ Xbf, bf16_t* __restrict__ Ybf,
                            float* __restrict__ x2, float* __restrict__ y2,
                            float* __restrict__ out) {
  int t = blockIdx.x * blockDim.x + threadIdx.x;   // 0..65535
  int half = t >> 15;                              // 0: X, 1: Y
  int r = (t >> 2) & (NROWS - 1);
  int part = t & 3;                                // 16 elems per thread
  const float* src = half ? Y : X;
  bf16_t* dst = half ? Ybf : Xbf;
  float* sq = half ? y2 : x2;

  const float4* p = (const float4*)(src + r * DDIM + part * 16);
  float4 v0 = p[0], v1 = p[1], v2 = p[2], v3 = p[3];
  float s = 0.f;
  s = fmaf(v0.x, v0.x, s); s = fmaf(v0.y, v0.y, s);
  s = fmaf(v0.z, v0.z, s); s = fmaf(v0.w, v0.w, s);
  s = fmaf(v1.x, v1.x, s); s = fmaf(v1.y, v1.y, s);
  s = fmaf(v1.z, v1.z, s); s = fmaf(v1.w, v1.w, s);
  s = fmaf(v2.x, v2.x, s); s = fmaf(v2.y, v2.y, s);
  s = fmaf(v2.z, v2.z, s); s = fmaf(v2.w, v2.w, s);
  s = fmaf(v3.x, v3.x, s); s = fmaf(v3.y, v3.y, s);
  s = fmaf(v3.z, v3.z, s); s = fmaf(v3.w, v3.w, s);

  bf16x8 h0 = {(bf16_t)v0.x, (bf16_t)v0.y, (bf16_t)v0.z, (bf16_t)v0.w,
               (bf16_t)v1.x, (bf16_t)v1.y, (bf16_t)v1.z, (bf16_t)v1.w};
  bf16x8 h1 = {(bf16_t)v2.x, (bf16_t)v2.y, (bf16_t)v2.z, (bf16_t)v2.w,
               (bf16_t)v3.x, (bf16_t)v3.y, (bf16_t)v3.z, (bf16_t)v3.w};
  *(bf16x8*)&dst[r * DDIM + part * 16] = h0;
  *(bf16x8*)&dst[r * DDIM + part * 16 + 8] = h1;

  s += __shfl_xor(s, 1, 64);
  s += __shfl_xor(s, 2, 64);
  if (part == 0) sq[r] = s;
  if (t == 0) out[0] = 0.f;
}

__global__ __launch_bounds__(256, 3)
void mine_kernel(const bf16_t* __restrict__ Xbf, const bf16_t* __restrict__ Ybf,
                 const float* __restrict__ x2g, const float* __restrict__ y2g,
                 float* __restrict__ rslab, float* __restrict__ cslab) {
  __shared__ bf16_t Ys[128 * LSTR];   // 18 KB; 3 blocks/CU -> 54 KB/CU

  const int tid = threadIdx.x;
  const int L = tid & 63;
  const int w = tid >> 6;
  const int lr = L & 15;
  const int q  = L >> 4;
  const int rh = w >> 1, ch = w & 1;
  const int itile = blockIdx.x & (ITILES - 1);
  const int slice = blockIdx.x >> 6;        // 0..31
  const int i0 = itile * 128;
  const int rgb = rh * 64, cgb = ch * 64;
  const int jbase = slice * (CHUNKS * 128);

  // ---- A fragments: register-persistent (32 VGPR) ----
  bf16x8 Af[8];
#pragma unroll
  for (int a = 0; a < 4; ++a) {
    int row = i0 + rgb + a * 16 + lr;
#pragma unroll
    for (int h = 0; h < 2; ++h)
      Af[a * 2 + h] = *(const bf16x8*)&Xbf[row * DDIM + h * 32 + q * 8];
  }
  float x2acc[4];                       // x2 of row a*16+lr (shfl at use)
#pragma unroll
  for (int a = 0; a < 4; ++a) x2acc[a] = x2g[i0 + rgb + a * 16 + lr];

  float rmin[16];
#pragma unroll
  for (int k = 0; k < 16; ++k) rmin[k] = INFINITY;

  for (int cc = 0; cc < CHUNKS; ++cc) {
    const int j0 = jbase + cc * 128;
    if (cc) __syncthreads();            // prior chunk's LDS fully consumed
    // ---- stage B chunk: pure bf16 copy, 4 x b128 per thread ----
#pragma unroll
    for (int p = 0; p < 4; ++p) {
      int f = p * 256 + tid;
      int r = f >> 3, c = f & 7;
      *(bf16x8*)&Ys[r * LSTR + c * 8] = *(const bf16x8*)&Ybf[(j0 + r) * DDIM + c * 8];
    }
    // issue y2 loads before the barrier so they drain with the staging loads
    float y2c[4];
#pragma unroll
    for (int b = 0; b < 4; ++b) y2c[b] = y2g[j0 + cgb + b * 16 + lr];
    __syncthreads();

    f32x4 acc[4][4];
#pragma unroll
    for (int a = 0; a < 4; ++a)
#pragma unroll
      for (int b = 0; b < 4; ++b) acc[a][b] = (f32x4){0.f, 0.f, 0.f, 0.f};

#pragma unroll
    for (int b = 0; b < 4; ++b) {
      bf16x8 B0 = *(const bf16x8*)&Ys[(cgb + b * 16 + lr) * LSTR + q * 8];
      bf16x8 B1 = *(const bf16x8*)&Ys[(cgb + b * 16 + lr) * LSTR + 32 + q * 8];
#pragma unroll
      for (int a = 0; a < 4; ++a) {
        acc[a][b] = __builtin_amdgcn_mfma_f32_16x16x32_bf16(Af[a * 2 + 0], B0, acc[a][b], 0, 0, 0);
        acc[a][b] = __builtin_amdgcn_mfma_f32_16x16x32_bf16(Af[a * 2 + 1], B1, acc[a][b], 0, 0, 0);
      }
    }

    // ---- epilogue (C/D: col = lr within 16-group, row = q*4+p) ----
    float cmin[4] = {INFINITY, INFINITY, INFINITY, INFINITY};
#pragma unroll
    for (int a = 0; a < 4; ++a)
#pragma unroll
      for (int p = 0; p < 4; ++p) {
        float x2v = __shfl(x2acc[a], q * 4 + p, 64);
        float t0 = fmaf(-2.f, acc[a][0][p], y2c[0]);
        float t1 = fmaf(-2.f, acc[a][1][p], y2c[1]);
        float t2 = fmaf(-2.f, acc[a][2][p], y2c[2]);
        float t3 = fmaf(-2.f, acc[a][3][p], y2c[3]);
        rmin[a * 4 + p] = fminf(rmin[a * 4 + p],
                                fminf(fminf(t0, t1), fminf(t2, t3)));
        cmin[0] = fminf(cmin[0], fmaf(-2.f, acc[a][0][p], x2v));
        cmin[1] = fminf(cmin[1], fmaf(-2.f, acc[a][1][p], x2v));
        cmin[2] = fminf(cmin[2], fmaf(-2.f, acc[a][2][p], x2v));
        cmin[3] = fminf(cmin[3], fmaf(-2.f, acc[a][3][p], x2v));
      }
#pragma unroll
    for (int b = 0; b < 4; ++b) {
      cmin[b] = fminf(cmin[b], __shfl_xor(cmin[b], 16, 64));
      cmin[b] = fminf(cmin[b], __shfl_xor(cmin[b], 32, 64));
    }
    float v = cmin[0], yv = y2c[0];
    if (q == 1) { v = cmin[1]; yv = y2c[1]; }
    else if (q == 2) { v = cmin[2]; yv = y2c[2]; }
    else if (q == 3) { v = cmin[3]; yv = y2c[3]; }
    cslab[(itile * 2 + rh) * NROWS + j0 + cgb + L] = v + yv;  // y2 folded
  }

  // ---- row mins: reduce across 16 col-lanes, fold x2, store once ----
#pragma unroll
  for (int a = 0; a < 4; ++a)
#pragma unroll
    for (int p = 0; p < 4; ++p) {
      float v = rmin[a * 4 + p];
      v = fminf(v, __shfl_xor(v, 1, 64));
      v = fminf(v, __shfl_xor(v, 2, 64));
      v = fminf(v, __shfl_xor(v, 4, 64));
      v = fminf(v, __shfl_xor(v, 8, 64));
      float x2v = __shfl(x2acc[a], q * 4 + p, 64);
      if (lr == 0)
        rslab[slice * (NROWS * 2) + (i0 + rgb + a * 16 + q * 4 + p) * 2 + ch] =
            v + x2v;
    }
}

// blocks [0,32): rows (256 each, 32x float2 coalesced). [32,160): cols
// (64 each, 4 segments x 32 partials, LDS combine). Slabs include x2/y2.
__global__ void finish_kernel(const float* __restrict__ rslab,
                              const float* __restrict__ cslab,
                              float* __restrict__ out) {
  const int b = blockIdx.x;
  const int tid = threadIdx.x;
  if (b < 32) {
    int row = b * 256 + tid;
    float m = INFINITY;
#pragma unroll
    for (int g = 0; g < SLICES; ++g) {
      float2 v = *(const float2*)&rslab[g * (NROWS * 2) + row * 2];
      m = fminf(m, fminf(v.x, v.y));
    }
    float v = sqrtf(fmaxf(m, 0.f)) * (1.0f / 8192.0f);
#pragma unroll
    for (int off = 32; off > 0; off >>= 1) v += __shfl_down(v, off, 64);
    __shared__ float partial[4];
    if ((tid & 63) == 0) partial[tid >> 6] = v;
    __syncthreads();
    if (tid == 0)
      atomicAdd(out, partial[0] + partial[1] + partial[2] + partial[3]);
  } else {
    int j = (b - 32) * 64 + (tid & 63);
    int seg = tid >> 6;
    float m = INFINITY;
#pragma unroll
    for (int k = 0; k < 32; ++k)
      m = fminf(m, cslab[(seg * 32 + k) * NROWS + j]);
    __shared__ float red[4][64];
    red[seg][tid & 63] = m;
    __syncthreads();
    if (tid < 64) {
      float mc = fminf(fminf(red[0][tid], red[1][tid]),
                       fminf(red[2][tid], red[3][tid]));
      float v = sqrtf(fmaxf(mc, 0.f)) * (1.0f / 8192.0f);
#pragma unroll
      for (int off = 32; off > 0; off >>= 1) v += __shfl_down(v, off, 64);
      if (tid == 0) atomicAdd(out, v);
    }
  }
}

extern "C" void kernel_launch(void* const* d_in, const int* in_sizes, int n_in,
                              void* d_out, int out_size, void* d_ws, size_t ws_size,
                              hipStream_t stream) {
  const float* X = (const float*)d_in[0];
  const float* Y = (const float*)d_in[1];
  float* out = (float*)d_out;

  char* wsb = (char*)d_ws;
  bf16_t* Xbf = (bf16_t*)wsb;                                // 1 MB
  bf16_t* Ybf = (bf16_t*)(wsb + (size_t)NROWS * DDIM * 2);   // 1 MB
  float* x2 = (float*)(wsb + 2 * (size_t)NROWS * DDIM * 2);
  float* y2 = x2 + NROWS;
  float* rslab = y2 + NROWS;                    // [32][8192][2]  2 MB
  float* cslab = rslab + SLICES * NROWS * 2;    // [128][8192]    4 MB

  prep_kernel<<<(2 * NROWS * 4) / 256, 256, 0, stream>>>(X, Y, Xbf, Ybf, x2, y2, out);
  mine_kernel<<<ITILES * SLICES, 256, 0, stream>>>(Xbf, Ybf, x2, y2, rslab, cslab);
  finish_kernel<<<160, 256, 0, stream>>>(rslab, cslab, out);
}